// Round 1
// baseline (667.238 us; speedup 1.0000x reference)
//
#include <hip/hip_runtime.h>
#include <math.h>

// Problem constants (match reference).
#define BB 512
#define KK 32
#define DD 768
#define NEG_INF (-1e30f)

// One block per sample b. 256 threads = 4 waves; wave w handles candidates
// k = w, w+4, ..., each lane reading 3 float4 (48 B) of the gathered weight
// row -> coalesced 16 B/lane. reps[b] staged in LDS once.
__global__ __launch_bounds__(256) void cbert_logits_kernel(
    const float* __restrict__ reps,      // [B, D]
    const float* __restrict__ weight,    // [N, D]
    const float* __restrict__ bias,      // [N]
    const int*   __restrict__ sense_ids, // [B, K]
    const int*   __restrict__ target_ids,// [B]
    float* __restrict__ out,             // [1 + B]: loss slot + correct flags
    float* __restrict__ nll_ws)          // [B] scratch
{
    __shared__ float4 s_repv[DD / 4];
    __shared__ float  s_logits[KK];

    const int b   = blockIdx.x;
    const int tid = threadIdx.x;

    // Stage reps row (768 floats = 192 float4) into LDS, coalesced.
    const float4* repv = reinterpret_cast<const float4*>(reps + (size_t)b * DD);
    for (int i = tid; i < DD / 4; i += 256) s_repv[i] = repv[i];
    __syncthreads();

    const int wave = tid >> 6;
    const int lane = tid & 63;

    for (int k = wave; k < KK; k += 4) {
        const int id = sense_ids[b * KK + k];
        float logit;
        if (id < 0) {
            logit = NEG_INF;
        } else {
            const float4* wrow =
                reinterpret_cast<const float4*>(weight + (size_t)id * DD);
            float acc = 0.0f;
            #pragma unroll
            for (int j = 0; j < 3; ++j) {
                const float4 w4 = wrow[j * 64 + lane];
                const float4 r4 = s_repv[j * 64 + lane];
                acc += w4.x * r4.x + w4.y * r4.y + w4.z * r4.z + w4.w * r4.w;
            }
            // 64-lane wave reduction.
            #pragma unroll
            for (int off = 32; off >= 1; off >>= 1)
                acc += __shfl_down(acc, off, 64);
            logit = acc + bias[id];
        }
        if (lane == 0) s_logits[k] = logit;
    }
    __syncthreads();

    if (tid == 0) {
        // max + argmax (first occurrence on ties, matching jnp.argmax).
        float m = s_logits[0];
        int   am = 0;
        for (int k = 1; k < KK; ++k) {
            const float v = s_logits[k];
            if (v > m) { m = v; am = k; }
        }
        float se = 0.0f;
        for (int k = 0; k < KK; ++k) se += expf(s_logits[k] - m);
        const int tgt = target_ids[b];
        const float nll = -(s_logits[tgt] - m - logf(se));
        nll_ws[b]    = nll;
        out[1 + b]   = (am == tgt) ? 1.0f : 0.0f;
    }
}

// Single-wave reduction of the 512 per-sample NLLs -> mean loss.
__global__ __launch_bounds__(64) void cbert_loss_kernel(
    const float* __restrict__ nll_ws, float* __restrict__ out)
{
    const int lane = threadIdx.x;
    float acc = 0.0f;
    for (int i = lane; i < BB; i += 64) acc += nll_ws[i];
    #pragma unroll
    for (int off = 32; off >= 1; off >>= 1)
        acc += __shfl_down(acc, off, 64);
    if (lane == 0) out[0] = acc / (float)BB;
}

extern "C" void kernel_launch(void* const* d_in, const int* in_sizes, int n_in,
                              void* d_out, int out_size, void* d_ws, size_t ws_size,
                              hipStream_t stream) {
    const float* reps       = (const float*)d_in[0];
    const float* weight     = (const float*)d_in[1];
    const float* bias       = (const float*)d_in[2];
    const int*   sense_ids  = (const int*)d_in[3];
    const int*   target_ids = (const int*)d_in[4];
    float* out    = (float*)d_out;
    float* nll_ws = (float*)d_ws;  // 512 floats

    cbert_logits_kernel<<<BB, 256, 0, stream>>>(
        reps, weight, bias, sense_ids, target_ids, out, nll_ws);
    cbert_loss_kernel<<<1, 64, 0, stream>>>(nll_ws, out);
}